// Round 7
// baseline (142.700 us; speedup 1.0000x reference)
//
#include <hip/hip_runtime.h>
#include <stdint.h>

#define NB 16
#define NC 128
#define NOC 128
#define NF 64
#define NT 256
#define NCTX 128
#define NTAPS 9
#define NFLAT 147456
#define TEMPR 30.0f

// LDS (16B chunk = 8 bf16 ic elems):
//   sx chunks: [kq:4][col:130]   col c <-> input t = t0 - 1 + c
//   sw chunks: [kx:3][kq:4][oc:128]
#define SXCOLS 130
#define SX_CHUNKS (4*SXCOLS)     // 520
#define SW_CHUNKS (3*4*NOC)      // 1536   -> total LDS = 2056*16 = 32896 B

typedef float f32x4 __attribute__((ext_vector_type(4)));
typedef __bf16 bf16x8 __attribute__((ext_vector_type(8)));

// ---------------- kernel 1: attention (16 x softmax over 4) ----------------
__global__ void attn_kernel(const float* __restrict__ g,
                            const float* __restrict__ dk,
                            const float* __restrict__ bias,
                            float* __restrict__ att) {
    int b = threadIdx.x;
    if (b >= NB) return;
    float r0 = bias[0], r1 = bias[1], r2 = bias[2], r3 = bias[3];
    const float* gb = g + b * NCTX;
    for (int c = 0; c < NCTX; ++c) {
        float gv = gb[c];
        r0 += gv * dk[c*4+0];
        r1 += gv * dk[c*4+1];
        r2 += gv * dk[c*4+2];
        r3 += gv * dk[c*4+3];
    }
    r0 *= (1.0f/TEMPR); r1 *= (1.0f/TEMPR); r2 *= (1.0f/TEMPR); r3 *= (1.0f/TEMPR);
    float mx = fmaxf(fmaxf(r0, r1), fmaxf(r2, r3));
    float e0 = expf(r0-mx), e1 = expf(r1-mx), e2 = expf(r2-mx), e3 = expf(r3-mx);
    float s = e0+e1+e2+e3;
    att[b*4+0] = e0/s; att[b*4+1] = e1/s; att[b*4+2] = e2/s; att[b*4+3] = e3/s;
}

// ------- kernel 2: blend 4 banks -> bf16 W K-major: [b][c4:4][tap:9][kq:4][oc:128][8]
// (tap = ky*3+kx, so a (c4,ky) slice of 3*4*128 chunks is contiguous)
__global__ void agg_kernel(const float* __restrict__ w,
                           const float* __restrict__ att,
                           unsigned short* __restrict__ wb) {
    int idx = blockIdx.x * 256 + threadIdx.x;   // 16*128*128 = 262144
    int ic = idx & 127;
    int oc = (idx >> 7) & 127;
    int b  = idx >> 14;
    float a0 = att[b*4+0], a1 = att[b*4+1], a2 = att[b*4+2], a3 = att[b*4+3];
    int d0 = (oc*NC + ic) * NTAPS;
    int c4 = ic >> 5;
    int kq = (ic >> 3) & 3;
    int e  = ic & 7;
    #pragma unroll
    for (int tap = 0; tap < NTAPS; ++tap) {
        float s = a0 * w[0*NFLAT + d0 + tap]
                + a1 * w[1*NFLAT + d0 + tap]
                + a2 * w[2*NFLAT + d0 + tap]
                + a3 * w[3*NFLAT + d0 + tap];
        __bf16 h = (__bf16)s;
        unsigned short u = *(unsigned short*)&h;
        int chunk = (tap * 4 + kq) * 128 + oc;                    // within c4 block
        wb[(((b * 4 + c4) * (NTAPS*4*NOC)) + chunk) * 8 + e] = u;
    }
}

// ------------------- kernel 3: MFMA implicit-GEMM conv -------------------
// Occupancy-first restructure: 256-thr blocks (4 waves), tile 128oc x 128pix,
// phase = (c4, ky) so LDS = 32.9 KB -> 3-4 blocks/CU. Cross-block overlap
// hides staging/barrier drains (R6 was 1 block/CU, 2 waves/SIMD, stall-bound).
// W staged with global_load_lds (16B, zero staging VGPRs, layout is linear).
__global__ __launch_bounds__(256) void conv_kernel(
        const float* __restrict__ x,
        const unsigned short* __restrict__ wb,
        float* __restrict__ out) {
    __shared__ __align__(16) unsigned short sx[SX_CHUNKS * 8];
    __shared__ __align__(16) unsigned short sw[SW_CHUNKS * 8];

    // bijective XCD swizzle: 2048 blocks -> 256 contiguous logical per XCD = 2 batches
    const int p  = blockIdx.x;
    const int lg = (p & 7) * 256 + (p >> 3);
    const int b  = lg >> 7;            // batch
    const int y  = (lg >> 1) & 63;     // output row
    const int t0 = (lg & 1) * 128;     // t half

    const int tid  = threadIdx.x;
    const int lane = tid & 63;
    const int wid  = tid >> 6;
    const int wpix = wid & 1;    // 64-pix half of the 128-pix tile
    const int woc  = wid >> 1;   // 64-oc half
    const int l15  = lane & 15;
    const int l4   = lane >> 4;

    f32x4 acc[4][4];
    #pragma unroll
    for (int m = 0; m < 4; ++m)
        #pragma unroll
        for (int n = 0; n < 4; ++n)
            acc[m][n] = (f32x4){0.f, 0.f, 0.f, 0.f};

    const float* xb = x + (b * NC) * (NF * NT);
    const unsigned short* wbb = wb + b * (NTAPS * NOC * NC);

    // X staging decomposition: unit u = tid + j*256 (j<2), 512 units
    //   epair = u&3 (bank wt 1), kq = (u>>2)&3 (bank wt 8), q = u>>4 (c = 4q+1+jj)
    // -> u32 LDS writes are 2-way max (free); global loads coalesce in 64B runs.
    const int se  = tid & 3;
    const int skq = (tid >> 2) & 3;

    // compute-phase LDS bases (per-thread constant)
    const unsigned short* const swA = sw + ((l4 * NOC) + woc * 64 + l15) * 8;
    const unsigned short* const sxp = sx + (l4 * SXCOLS + wpix * 64 + l15) * 8;

    for (int c4 = 0; c4 < 4; ++c4) {
        #pragma unroll
        for (int ky = 0; ky < 3; ++ky) {
            const int iy = y - 1 + ky;
            const bool rowok = (unsigned)iy < (unsigned)NF;
            __syncthreads();   // previous compute done reading sx/sw

            // ---- stage X main cols c=1..128: 2 units/thread
            #pragma unroll
            for (int j = 0; j < 2; ++j) {
                int u  = tid + j * 256;
                int q  = u >> 4;                       // 0..31
                int ic = c4 * 32 + skq * 8 + se * 2;
                f32x4 v0 = (f32x4){0.f,0.f,0.f,0.f};
                f32x4 v1 = v0;
                if (rowok) {
                    const float* src = xb + (ic * NF + iy) * NT + t0 + q * 4;
                    v0 = *(const f32x4*)src;
                    v1 = *(const f32x4*)(src + NF * NT);
                }
                unsigned short* dst = sx + (skq * SXCOLS + q * 4 + 1) * 8 + se * 2;
                #pragma unroll
                for (int jj = 0; jj < 4; ++jj) {
                    __bf16 h0 = (__bf16)v0[jj];
                    __bf16 h1 = (__bf16)v1[jj];
                    unsigned pk = (unsigned)*(unsigned short*)&h0
                                | ((unsigned)*(unsigned short*)&h1 << 16);
                    *(unsigned*)(dst + jj * 8) = pk;
                }
            }
            // ---- stage X boundary cols c=0 and c=129 (32 units)
            if (tid < 32) {
                int e    = tid & 3;
                int kq   = (tid >> 2) & 3;
                int side = tid >> 4;
                int c    = side ? (SXCOLS - 1) : 0;
                int t    = t0 - 1 + c;
                int ic   = c4 * 32 + kq * 8 + e * 2;
                float f0 = 0.f, f1 = 0.f;
                if (rowok && (unsigned)t < (unsigned)NT) {
                    const float* src = xb + (ic * NF + iy) * NT + t;
                    f0 = src[0];
                    f1 = src[NF * NT];
                }
                __bf16 h0 = (__bf16)f0;
                __bf16 h1 = (__bf16)f1;
                unsigned pk = (unsigned)*(unsigned short*)&h0
                            | ((unsigned)*(unsigned short*)&h1 << 16);
                *(unsigned*)(sx + (kq * SXCOLS + c) * 8 + e * 2) = pk;
            }

            // ---- stage W: 1536 chunks via async global_load_lds (16B each)
            {
                const unsigned short* wsrc = wbb + ((c4 * 9 + ky * 3) * 4 * NOC) * 8;
                #pragma unroll
                for (int j = 0; j < 6; ++j) {
                    const int chunk = j * 256 + wid * 64;   // wave-uniform LDS base
                    __builtin_amdgcn_global_load_lds(
                        (const __attribute__((address_space(1))) unsigned int*)
                            (const void*)(wsrc + (chunk + lane) * 8),
                        (__attribute__((address_space(3))) unsigned int*)
                            (void*)(sw + chunk * 8),
                        16, 0, 0);
                }
            }
            __syncthreads();   // implies vmcnt(0): W + X visible

            // ---- compute: 3 kx taps x (4 A + 4 B b128 reads, 16 MFMA) per wave
            #pragma unroll
            for (int kx = 0; kx < 3; ++kx) {
                bf16x8 af[4], bfv[4];
                #pragma unroll
                for (int m = 0; m < 4; ++m)
                    af[m] = *(const bf16x8*)(swA + (kx * 4 * NOC + m * 16) * 8);
                #pragma unroll
                for (int n = 0; n < 4; ++n)
                    bfv[n] = *(const bf16x8*)(sxp + (kx + n * 16) * 8);
                #pragma unroll
                for (int m = 0; m < 4; ++m)
                    #pragma unroll
                    for (int n = 0; n < 4; ++n)
                        acc[m][n] = __builtin_amdgcn_mfma_f32_16x16x32_bf16(
                            af[m], bfv[n], acc[m][n], 0, 0, 0);
            }
        }
    }

    // ---- epilogue: D[row=oc=(l>>4)*4+r][col=pix=l&15]
    #pragma unroll
    for (int m = 0; m < 4; ++m) {
        int ocb = woc * 64 + m * 16 + l4 * 4;
        #pragma unroll
        for (int r = 0; r < 4; ++r) {
            float* orow = out + ((b * NOC + ocb + r) * NF + y) * NT + t0;
            #pragma unroll
            for (int n = 0; n < 4; ++n)
                orow[wpix * 64 + n * 16 + l15] = acc[m][n][r];
        }
    }
}

extern "C" void kernel_launch(void* const* d_in, const int* in_sizes, int n_in,
                              void* d_out, int out_size, void* d_ws, size_t ws_size,
                              hipStream_t stream) {
    const float* x    = (const float*)d_in[0];
    const float* g    = (const float*)d_in[1];
    const float* dk   = (const float*)d_in[2];
    const float* bias = (const float*)d_in[3];
    const float* w    = (const float*)d_in[4];
    float* out = (float*)d_out;

    float* att = (float*)d_ws;                                  // 64 floats
    unsigned short* wb = (unsigned short*)((char*)d_ws + 256);  // 16*9*128*128 bf16, K-major

    attn_kernel<<<dim3(1), dim3(64), 0, stream>>>(g, dk, bias, att);
    agg_kernel<<<dim3(1024), dim3(256), 0, stream>>>(w, att, wb);
    conv_kernel<<<dim3(2048), dim3(256), 0, stream>>>(x, wb, out);
}

// Round 8
// 124.836 us; speedup vs baseline: 1.1431x; 1.1431x over previous
//
#include <hip/hip_runtime.h>
#include <stdint.h>

#define NB 16
#define NC 128
#define NOC 128
#define NF 64
#define NT 256
#define NCTX 128
#define NTAPS 9
#define NFLAT 147456
#define TEMPR 30.0f

// LDS per buffer (16B chunk = 8 bf16 ic elems):
//   sw chunks: [kx:3][kq:4][oc:128] = 1536 chunks (one (c4,ky) W slice)
//   sx chunks: [kq:4][col:130]      =  520 chunks (one x row, 128 t + 2 halo)
#define SW_CH 1536
#define SX_CH 520
#define BUF_CH (SW_CH + SX_CH)   // 2056 chunks = 32896 B ; x2 buffers = 65792 B

typedef float f32x4 __attribute__((ext_vector_type(4)));
typedef __bf16 bf16x8 __attribute__((ext_vector_type(8)));

// ---------------- kernel 1: attention (16 x softmax over 4) ----------------
__global__ void attn_kernel(const float* __restrict__ g,
                            const float* __restrict__ dk,
                            const float* __restrict__ bias,
                            float* __restrict__ att) {
    int b = threadIdx.x;
    if (b >= NB) return;
    float r0 = bias[0], r1 = bias[1], r2 = bias[2], r3 = bias[3];
    const float* gb = g + b * NCTX;
    for (int c = 0; c < NCTX; ++c) {
        float gv = gb[c];
        r0 += gv * dk[c*4+0];
        r1 += gv * dk[c*4+1];
        r2 += gv * dk[c*4+2];
        r3 += gv * dk[c*4+3];
    }
    r0 *= (1.0f/TEMPR); r1 *= (1.0f/TEMPR); r2 *= (1.0f/TEMPR); r3 *= (1.0f/TEMPR);
    float mx = fmaxf(fmaxf(r0, r1), fmaxf(r2, r3));
    float e0 = expf(r0-mx), e1 = expf(r1-mx), e2 = expf(r2-mx), e3 = expf(r3-mx);
    float s = e0+e1+e2+e3;
    att[b*4+0] = e0/s; att[b*4+1] = e1/s; att[b*4+2] = e2/s; att[b*4+3] = e3/s;
}

// ------- kernel 2: blend 4 banks -> bf16 W K-major: [b][c4:4][tap:9][kq:4][oc:128][8]
__global__ void agg_kernel(const float* __restrict__ w,
                           const float* __restrict__ att,
                           unsigned short* __restrict__ wb) {
    int idx = blockIdx.x * 256 + threadIdx.x;   // 16*128*128 = 262144
    int ic = idx & 127;
    int oc = (idx >> 7) & 127;
    int b  = idx >> 14;
    float a0 = att[b*4+0], a1 = att[b*4+1], a2 = att[b*4+2], a3 = att[b*4+3];
    int d0 = (oc*NC + ic) * NTAPS;
    int c4 = ic >> 5;
    int kq = (ic >> 3) & 3;
    int e  = ic & 7;
    #pragma unroll
    for (int tap = 0; tap < NTAPS; ++tap) {
        float s = a0 * w[0*NFLAT + d0 + tap]
                + a1 * w[1*NFLAT + d0 + tap]
                + a2 * w[2*NFLAT + d0 + tap]
                + a3 * w[3*NFLAT + d0 + tap];
        __bf16 h = (__bf16)s;
        unsigned short u = *(unsigned short*)&h;
        int chunk = (tap * 4 + kq) * 128 + oc;                    // within c4 block
        wb[(((b * 4 + c4) * (NTAPS*4*NOC)) + chunk) * 8 + e] = u;
    }
}

// ------------------- kernel 3: MFMA implicit-GEMM conv -------------------
// T3/T4 double-buffered 12-phase pipeline, phase = (c4, ky):
//   barrier -> [issue X(p+1)->regs, W(p+1)->glob_load_lds buf^1]
//   -> compute buf (3 kx x 16 MFMA, setprio) -> vmcnt(0) -> ds_write X regs -> barrier
// LDS 2x33KB -> 2 blocks/CU (256 thr, 4 waves, tile 128oc x 128pix, acc[4][4]).
// Register tier: keep unified (VGPR + 64 AGPR) < 192 so 2 waves/SIMD hold.
__global__ __launch_bounds__(256) void conv_kernel(
        const float* __restrict__ x,
        const unsigned short* __restrict__ wb,
        float* __restrict__ out) {
    __shared__ __align__(16) unsigned short lds[2 * BUF_CH * 8];

    // bijective XCD swizzle: 2048 blocks -> 256 contiguous logical per XCD = 2 batches
    const int p_  = blockIdx.x;
    const int lg  = (p_ & 7) * 256 + (p_ >> 3);
    const int b   = lg >> 7;            // batch
    const int y   = (lg >> 1) & 63;     // output row
    const int t0  = (lg & 1) * 128;     // t half

    const int tid  = threadIdx.x;
    const int lane = tid & 63;
    const int wid  = tid >> 6;
    const int wpix = wid & 1;    // 64-pix half
    const int woc  = wid >> 1;   // 64-oc half
    const int l15  = lane & 15;
    const int l4   = lane >> 4;

    f32x4 acc[4][4];
    #pragma unroll
    for (int m = 0; m < 4; ++m)
        #pragma unroll
        for (int n = 0; n < 4; ++n)
            acc[m][n] = (f32x4){0.f, 0.f, 0.f, 0.f};

    const float* xb = x + (b * NC) * (NF * NT);
    const unsigned short* wbb = wb + b * (NTAPS * NOC * NC);

    // X staging decomposition: q=tid>>4 (8-col group), kq=(tid>>2)&3, e=tid&3 (ic pair)
    const int sq  = tid >> 4;
    const int skq = (tid >> 2) & 3;
    const int se  = tid & 3;

    // X prefetch regs (one row slice: 2 ic x 8 cols)
    f32x4 v00, v01, v10, v11;
    float bf0 = 0.f, bf1 = 0.f;         // boundary col (tid<32 only)

    auto issue_x = [&](int c4, int ky) {
        const int iy = y - 1 + ky;
        const bool rowok = (unsigned)iy < (unsigned)NF;
        const int ic0 = c4 * 32 + skq * 8 + se * 2;
        v00 = (f32x4){0.f,0.f,0.f,0.f}; v01 = v00; v10 = v00; v11 = v00;
        if (rowok) {
            const float* src = xb + (ic0 * NF + iy) * NT + t0 + sq * 8;
            v00 = *(const f32x4*)src;
            v01 = *(const f32x4*)(src + 4);
            v10 = *(const f32x4*)(src + NF * NT);
            v11 = *(const f32x4*)(src + NF * NT + 4);
        }
        bf0 = 0.f; bf1 = 0.f;
        if (tid < 32) {
            const int side = (tid >> 4) & 1;
            const int c    = side ? 129 : 0;
            const int t    = t0 + c - 1;
            const int ic   = c4 * 32 + skq * 8 + se * 2;
            if (rowok && (unsigned)t < (unsigned)NT) {
                const float* src = xb + (ic * NF + iy) * NT + t;
                bf0 = src[0];
                bf1 = src[NF * NT];
            }
        }
    };

    auto issue_w = [&](int c4, int ky, unsigned short* swb) {
        const unsigned short* slice = wbb + (c4 * 4608 + ky * 1536) * 8;
        #pragma unroll
        for (int j = 0; j < 6; ++j) {
            const int rid = j * 4 + wid;               // 24 runs of 64 chunks
            __builtin_amdgcn_global_load_lds(
                (const __attribute__((address_space(1))) unsigned int*)
                    (const void*)(slice + (rid * 64 + lane) * 8),
                (__attribute__((address_space(3))) unsigned int*)
                    (void*)(swb + rid * 64 * 8),
                16, 0, 0);
        }
    };

    auto write_x = [&](unsigned short* sxb) {
        unsigned short* dst = sxb + (skq * 130 + sq * 8 + 1) * 8 + se * 2;
        #pragma unroll
        for (int jj = 0; jj < 4; ++jj) {
            __bf16 h0 = (__bf16)v00[jj];
            __bf16 h1 = (__bf16)v10[jj];
            unsigned pk = (unsigned)*(unsigned short*)&h0
                        | ((unsigned)*(unsigned short*)&h1 << 16);
            *(unsigned*)(dst + jj * 8) = pk;
        }
        #pragma unroll
        for (int jj = 0; jj < 4; ++jj) {
            __bf16 h0 = (__bf16)v01[jj];
            __bf16 h1 = (__bf16)v11[jj];
            unsigned pk = (unsigned)*(unsigned short*)&h0
                        | ((unsigned)*(unsigned short*)&h1 << 16);
            *(unsigned*)(dst + (4 + jj) * 8) = pk;
        }
        if (tid < 32) {
            const int side = (tid >> 4) & 1;
            const int c    = side ? 129 : 0;
            __bf16 h0 = (__bf16)bf0;
            __bf16 h1 = (__bf16)bf1;
            unsigned pk = (unsigned)*(unsigned short*)&h0
                        | ((unsigned)*(unsigned short*)&h1 << 16);
            *(unsigned*)(sxb + (skq * 130 + c) * 8 + se * 2) = pk;
        }
    };

    // ---- prologue: stage phase 0 into buffer 0
    issue_x(0, 0);
    issue_w(0, 0, lds);
    asm volatile("s_waitcnt vmcnt(0)" ::: "memory");
    write_x(lds + SW_CH * 8);
    __syncthreads();

    #pragma unroll
    for (int c4 = 0; c4 < 4; ++c4) {
        #pragma unroll
        for (int ky = 0; ky < 3; ++ky) {
            const int ph   = c4 * 3 + ky;
            const int last = (ph == 11);
            unsigned short* cur = lds + (ph & 1) * (BUF_CH * 8);
            unsigned short* nxt = lds + ((ph & 1) ^ 1) * (BUF_CH * 8);
            unsigned short* swb = cur;
            unsigned short* sxb = cur + SW_CH * 8;

            // issue next phase's loads: they fly under the MFMA below
            if (!last) {
                const int nc4 = (ph + 1) / 3;
                const int nky = (ph + 1) % 3;
                issue_x(nc4, nky);
                issue_w(nc4, nky, nxt);
            }

            // compute: 3 kx x (4 A + 4 B b128 reads, 16 MFMA)
            #pragma unroll
            for (int kx = 0; kx < 3; ++kx) {
                bf16x8 af[4], bfv[4];
                #pragma unroll
                for (int m = 0; m < 4; ++m)
                    af[m] = *(const bf16x8*)(swb +
                        ((kx * 4 + l4) * 128 + woc * 64 + m * 16 + l15) * 8);
                #pragma unroll
                for (int n = 0; n < 4; ++n)
                    bfv[n] = *(const bf16x8*)(sxb +
                        (l4 * 130 + wpix * 64 + n * 16 + l15 + kx) * 8);
                __builtin_amdgcn_s_setprio(1);
                #pragma unroll
                for (int m = 0; m < 4; ++m)
                    #pragma unroll
                    for (int n = 0; n < 4; ++n)
                        acc[m][n] = __builtin_amdgcn_mfma_f32_16x16x32_bf16(
                            af[m], bfv[n], acc[m][n], 0, 0, 0);
                __builtin_amdgcn_s_setprio(0);
            }

            if (!last) {
                // gll for next phase must land + X regs ready before ds_write/use
                asm volatile("s_waitcnt vmcnt(0)" ::: "memory");
                write_x(nxt + SW_CH * 8);
            }
            __syncthreads();
        }
    }

    // ---- epilogue: D[row=oc=(l>>4)*4+r][col=pix=l&15]
    #pragma unroll
    for (int m = 0; m < 4; ++m) {
        int ocb = woc * 64 + m * 16 + l4 * 4;
        #pragma unroll
        for (int r = 0; r < 4; ++r) {
            float* orow = out + ((b * NOC + ocb + r) * NF + y) * NT + t0;
            #pragma unroll
            for (int n = 0; n < 4; ++n)
                orow[wpix * 64 + n * 16 + l15] = acc[m][n][r];
        }
    }
}

extern "C" void kernel_launch(void* const* d_in, const int* in_sizes, int n_in,
                              void* d_out, int out_size, void* d_ws, size_t ws_size,
                              hipStream_t stream) {
    const float* x    = (const float*)d_in[0];
    const float* g    = (const float*)d_in[1];
    const float* dk   = (const float*)d_in[2];
    const float* bias = (const float*)d_in[3];
    const float* w    = (const float*)d_in[4];
    float* out = (float*)d_out;

    float* att = (float*)d_ws;                                  // 64 floats
    unsigned short* wb = (unsigned short*)((char*)d_ws + 256);  // 16*9*128*128 bf16, K-major

    attn_kernel<<<dim3(1), dim3(64), 0, stream>>>(g, dk, bias, att);
    agg_kernel<<<dim3(1024), dim3(256), 0, stream>>>(w, att, wb);
    conv_kernel<<<dim3(2048), dim3(256), 0, stream>>>(x, wb, out);
}